// Round 4
// baseline (301.160 us; speedup 1.0000x reference)
//
#include <hip/hip_runtime.h>

// MinimalSSM via MFMA, scan-free: Bu = U@B^T (bf16 MFMA), then
// H[t,s] = a_s^t * ( cumsum_{tau<=t} a_s^{-tau} Bu[tau,s] + a_s*c0_s )
// where the cumsum is a triangular ONES matrix-multiply (state-independent)
// done on MFMA with in-register 0/1 B-fragments. Y = H@C^T + U@D^T.
// All LDS traffic is in 16B fragment granules with XOR swizzle; the Du
// B-fragments alias the staged U A-fragments byte-for-byte.
// K1: chunk aggregates (in-register weighted reduce). K2: serial carry scan
// over 2048 chunks, in-place (agg -> carry). K3: the fused chunk kernel.

#define TT   262144
#define DIN  64
#define DS   128
#define DTC  0.01f
#define L    128
#define NG   (TT / L)        // 2048 chunks

typedef short  s8v  __attribute__((ext_vector_type(8)));
typedef short  s4v  __attribute__((ext_vector_type(4)));
typedef float  f4v  __attribute__((ext_vector_type(4)));

__device__ __forceinline__ unsigned short f2bf(float f) {
    unsigned u = __float_as_uint(f);
    u += 0x7fffu + ((u >> 16) & 1u);        // round-to-nearest-even
    return (unsigned short)(u >> 16);
}

__device__ __forceinline__ s8v pack8(float4 a, float4 b) {
    union { unsigned short u[8]; s8v v; } r;
    r.u[0] = f2bf(a.x); r.u[1] = f2bf(a.y); r.u[2] = f2bf(a.z); r.u[3] = f2bf(a.w);
    r.u[4] = f2bf(b.x); r.u[5] = f2bf(b.y); r.u[6] = f2bf(b.z); r.u[7] = f2bf(b.w);
    return r.v;
}

__device__ __forceinline__ s4v pack4(float x, float y, float z, float w) {
    union { unsigned short u[4]; s4v v; } r;
    r.u[0] = f2bf(x); r.u[1] = f2bf(y); r.u[2] = f2bf(z); r.u[3] = f2bf(w);
    return r.v;
}

// Fragment-granule LDS layout for matrix X[row][col] (bf16, 8-col granules):
// ushort index = ((rtile*NCO + co)*16 + (mf ^ (co&15))) * 8,  rtile = row>>4,
// co = col>>3, mf = row&15. XOR swizzle keeps frag reads/writes <=2..4-way.
__device__ __forceinline__ int gidx(int NCO, int rtile, int co, int mf) {
    return (((rtile * NCO + co) << 4) + (mf ^ (co & 15))) << 3;
}

// 16B fragment read: lane(q,m) -> rows 16*rtile+m, cols (4*kt+q)*8..+7
__device__ __forceinline__ s8v ldfrag(const unsigned short* S, int NCO,
                                      int rtile, int kt, int q, int m) {
    return *(const s8v*)&S[gidx(NCO, rtile, kt * 4 + q, m)];
}

// Stage U chunk (128 x 64 fp32) -> bf16 A-frag granules in sA.
// u = (mt, m, co): consecutive tids read contiguous global (256B per 8 thr).
__device__ __forceinline__ void stage_U(const float* __restrict__ Ug,
                                        unsigned short* __restrict__ sA,
                                        int tid) {
    #pragma unroll
    for (int p = 0; p < 2; ++p) {
        int u  = tid + p * 512;
        int co = u & 7, m = (u >> 3) & 15, mt = u >> 7;
        const float4* gp = (const float4*)(Ug + (mt * 16 + m) * DIN + co * 8);
        *(s8v*)&sA[gidx(8, mt, co, m)] = pack8(gp[0], gp[1]);
    }
}

// B-operand fragment from row-major M (ld floats): lane(q,m) with row arg
// holds M[row][k0+q*8 .. +7]  (row plays the N index).
__device__ __forceinline__ s8v load_bfrag(const float* __restrict__ M,
                                          int row, int k0, int ld) {
    const float4* p = (const float4*)(M + row * ld + k0);
    return pack8(p[0], p[1]);
}

// ---------------------------------------------------------------- K1
// agg[g][s] = sum_t a_s^(L-1-t) Bu[t,s] from MFMA accumulators + q-butterfly.
__global__ __launch_bounds__(512, 4) void ssm_k1(
    const float* __restrict__ U, const float* __restrict__ Alog,
    const float* __restrict__ B, float* __restrict__ agg)
{
    __shared__ __align__(16) unsigned short sA[8192];   // 16 KB
    const int g    = blockIdx.x;
    const int tid  = threadIdx.x;
    const int lane = tid & 63;
    const int w    = tid >> 6;          // wave = 16-state strip
    const int q    = lane >> 4, m = lane & 15;
    const int s    = 16 * w + m;

    stage_U(U + (size_t)g * L * DIN, sA, tid);

    s8v Bf[2];
    #pragma unroll
    for (int ks = 0; ks < 2; ++ks)
        Bf[ks] = load_bfrag(B, s, ks * 32 + q * 8, DIN);

    const float cA = Alog[s] * DTC;
    __syncthreads();

    // weight(t) = exp(cA*(127-t)), t = 16mt + 4q + r
    float ainv = __expf(-cA);
    float a16i = __expf(-16.f * cA);
    float wmt  = __expf(cA * (float)(127 - 4 * q));
    float wsum = 0.f;
    #pragma unroll
    for (int mt = 0; mt < 8; ++mt) {
        f4v acc = (f4v){0.f, 0.f, 0.f, 0.f};
        #pragma unroll
        for (int ks = 0; ks < 2; ++ks)
            acc = __builtin_amdgcn_mfma_f32_16x16x32_bf16(
                ldfrag(sA, 8, mt, ks, q, m), Bf[ks], acc, 0, 0, 0);
        float wr = wmt;
        #pragma unroll
        for (int r = 0; r < 4; ++r) {
            wsum = fmaf(wr, acc[r], wsum);
            wr *= ainv;
        }
        wmt *= a16i;
    }
    wsum += __shfl_xor(wsum, 16, 64);
    wsum += __shfl_xor(wsum, 32, 64);
    if (q == 0) agg[(size_t)g * DS + s] = wsum;
}

// ---------------------------------------------------------------- K2
// In-place serial scan: agg[g] (chunk aggregates) -> carry into chunk g.
__global__ void ssm_k2(const float* __restrict__ Alog, const float* __restrict__ h0,
                       float* agg, float* __restrict__ hfin)
{
    const int s = threadIdx.x;                            // 128 threads
    const float aL = __expf(Alog[s] * (DTC * (float)L));  // a^L
    float c = h0[s];
    #pragma unroll 8
    for (int g = 0; g < NG; ++g) {
        float v = agg[(size_t)g * DS + s];
        agg[(size_t)g * DS + s] = c;      // carry INTO chunk g
        c = fmaf(aL, c, v);
    }
    hfin[s] = c;
}

// ---------------------------------------------------------------- K3
__global__ __launch_bounds__(512, 6) void ssm_k3(
    const float* __restrict__ U, const float* __restrict__ Alog,
    const float* __restrict__ B, const float* __restrict__ C,
    const float* __restrict__ Dm, const float* __restrict__ carry,
    float* __restrict__ Y)
{
    __shared__ __align__(16) unsigned short sA[8192];    // 16 KB, U frags
    __shared__ __align__(16) unsigned short sT[16384];   // 32 KB, Bu'^T then H^T
    __shared__ float sCA[DS];
    __shared__ float sDc[DS];

    const int g    = blockIdx.x;
    const int tid  = threadIdx.x;
    const int lane = tid & 63;
    const int w    = tid >> 6;
    const int q    = lane >> 4, m = lane & 15;

    // GEMM1 B-frags (wave = s-strip w)
    s8v Bf[2];
    #pragma unroll
    for (int ks = 0; ks < 2; ++ks)
        Bf[ks] = load_bfrag(B, 16 * w + m, ks * 32 + q * 8, DIN);
    const float cA = Alog[16 * w + m] * DTC;

    stage_U(U + (size_t)g * L * DIN, sA, tid);
    if (tid < DS) {
        float ca = Alog[tid] * DTC;
        sCA[tid] = ca;
        sDc[tid] = __expf(ca) * carry[(size_t)g * DS + tid];   // a_s * c0_s
    }
    __syncthreads();                                     // B1

    // ---- GEMM1 + scale by a_s^-t + transpose-store Bu'^T[s][t]
    {
        float ainv = __expf(-cA);
        float a16i = __expf(-16.f * cA);
        float fmt  = __expf(-cA * (float)(4 * q));       // t = 16mt+4q+r
        #pragma unroll
        for (int mt = 0; mt < 8; ++mt) {
            f4v acc = (f4v){0.f, 0.f, 0.f, 0.f};
            #pragma unroll
            for (int ks = 0; ks < 2; ++ks)
                acc = __builtin_amdgcn_mfma_f32_16x16x32_bf16(
                    ldfrag(sA, 8, mt, ks, q, m), Bf[ks], acc, 0, 0, 0);
            float f0 = fmt, f1 = f0 * ainv, f2 = f1 * ainv, f3 = f2 * ainv;
            s4v pk = pack4(acc[0] * f0, acc[1] * f1, acc[2] * f2, acc[3] * f3);
            // X[s=16w+m][t]: rt=w, co=t>>3=2mt+(q>>1), in-granule (q&1)*4+r
            *(s4v*)&sT[gidx(16, w, mt * 2 + (q >> 1), m) + (q & 1) * 4] = pk;
            fmt *= a16i;
        }
    }
    __syncthreads();                                     // B2

    // ---- Tri-GEMM: H'^T[s,t] = sum_tau Bu'^T[s,tau] * [tau<=t]
    // wave = t-strip w (t = 16w+m). One partial frag at kb=KBmax, ones below.
    const int KBmax = w >> 1;
    const int thr   = m + 16 * (w & 1);
    s8v ones, part;
    {
        union { unsigned short u[8]; s8v v; } o, p;
        #pragma unroll
        for (int j = 0; j < 8; ++j) {
            o.u[j] = 0x3F80;
            p.u[j] = (q * 8 + j <= thr) ? 0x3F80 : 0;
        }
        ones = o.v; part = p.v;
    }
    const float tf = (float)(16 * w + m);
    s4v pk[8];                                           // packed H^T rows
    #pragma unroll
    for (int grp = 0; grp < 2; ++grp) {
        f4v acc[4];
        #pragma unroll
        for (int i = 0; i < 4; ++i) acc[i] = (f4v){0.f, 0.f, 0.f, 0.f};
        for (int kb = 0; kb <= KBmax; ++kb) {
            s8v bfr = (kb < KBmax) ? ones : part;
            #pragma unroll
            for (int msl = 0; msl < 4; ++msl)
                acc[msl] = __builtin_amdgcn_mfma_f32_16x16x32_bf16(
                    ldfrag(sT, 16, grp * 4 + msl, kb, q, m), bfr, acc[msl], 0, 0, 0);
        }
        #pragma unroll
        for (int msl = 0; msl < 4; ++msl) {              // s = 16ms+4q+r
            const int ms = grp * 4 + msl;
            const float4 cav = *(const float4*)&sCA[16 * ms + 4 * q];
            const float4 dcv = *(const float4*)&sDc[16 * ms + 4 * q];
            pk[grp * 4 + msl] = pack4(
                __expf(cav.x * tf) * (acc[msl][0] + dcv.x),
                __expf(cav.y * tf) * (acc[msl][1] + dcv.y),
                __expf(cav.z * tf) * (acc[msl][2] + dcv.z),
                __expf(cav.w * tf) * (acc[msl][3] + dcv.w));
        }
    }

    // issue C/D raw loads now; latency hidden by barriers + sT writes
    const int mi = w & 3, th = w >> 2;
    float4 craw[4][2], draw[2][2];
    #pragma unroll
    for (int ks = 0; ks < 4; ++ks) {
        const float4* p = (const float4*)(C + (16 * mi + m) * DS + ks * 32 + q * 8);
        craw[ks][0] = p[0]; craw[ks][1] = p[1];
    }
    #pragma unroll
    for (int ks = 0; ks < 2; ++ks) {
        const float4* p = (const float4*)(Dm + (16 * mi + m) * DIN + ks * 32 + q * 8);
        draw[ks][0] = p[0]; draw[ks][1] = p[1];
    }

    __syncthreads();                                     // B3: Bu' reads done
    #pragma unroll
    for (int ms = 0; ms < 8; ++ms)                       // H^T[t][s] over sT
        *(s4v*)&sT[gidx(16, w, ms * 2 + (q >> 1), m) + (q & 1) * 4] = pk[ms];
    __syncthreads();                                     // B4

    // ---- GEMM2: Y[t,i] = H@C^T + U@D^T, computed as (M=i, N=t) tiles.
    s8v Cf[4], Df[2];
    #pragma unroll
    for (int ks = 0; ks < 4; ++ks) Cf[ks] = pack8(craw[ks][0], craw[ks][1]);
    #pragma unroll
    for (int ks = 0; ks < 2; ++ks) Df[ks] = pack8(draw[ks][0], draw[ks][1]);

    float* Yb = Y + (size_t)g * L * DIN;
    #pragma unroll
    for (int nn = 0; nn < 4; ++nn) {
        const int nt2 = th * 4 + nn;
        f4v acc2 = (f4v){0.f, 0.f, 0.f, 0.f};
        #pragma unroll
        for (int ks = 0; ks < 4; ++ks)
            acc2 = __builtin_amdgcn_mfma_f32_16x16x32_bf16(
                Cf[ks], ldfrag(sT, 16, nt2, ks, q, m), acc2, 0, 0, 0);
        #pragma unroll
        for (int ks = 0; ks < 2; ++ks)                   // Du: U frags as B
            acc2 = __builtin_amdgcn_mfma_f32_16x16x32_bf16(
                Df[ks], ldfrag(sA, 8, nt2, ks, q, m), acc2, 0, 0, 0);
        // D-layout: col = t = 16nt2+m, rows i = 16mi+4q+r -> one float4/lane
        *(f4v*)(Yb + (16 * nt2 + m) * DIN + 16 * mi + 4 * q) = acc2;
    }
}

// ---------------------------------------------------------------- launch
extern "C" void kernel_launch(void* const* d_in, const int* in_sizes, int n_in,
                              void* d_out, int out_size, void* d_ws, size_t ws_size,
                              hipStream_t stream)
{
    const float* U    = (const float*)d_in[0];
    const float* Alog = (const float*)d_in[1];
    const float* B    = (const float*)d_in[2];
    const float* C    = (const float*)d_in[3];
    const float* Dm   = (const float*)d_in[4];
    const float* h0   = (const float*)d_in[5];

    float* out  = (float*)d_out;
    float* Yp   = out;                        // T*DIN
    float* hfin = out + (size_t)TT * DIN;     // 128

    float* agg = (float*)d_ws;                // NG*DS fp32 = 1 MB (agg->carry)

    ssm_k1<<<NG, 512, 0, stream>>>(U, Alog, B, agg);
    ssm_k2<<<1, DS, 0, stream>>>(Alog, h0, agg, hfin);
    ssm_k3<<<NG, 512, 0, stream>>>(U, Alog, B, C, Dm, agg, Yp);
}

// Round 5
// 205.304 us; speedup vs baseline: 1.4669x; 1.4669x over previous
//
#include <hip/hip_runtime.h>

// MinimalSSM via MFMA, scan-free: Bu = U@B^T (bf16 MFMA), then
// H[t,s] = a_s^t * ( cumsum_{tau<=t} a_s^{-tau} Bu[tau,s] + a_s*c0_s )
// (cumsum = triangular ones-GEMM on MFMA). Y = H@C^T + U@D^T.
// R5: segment carry hierarchy restored (K2 over 2048 chunks was a 120us
// latency chain): K1 -> agg + atomic segAgg (SEGL=16), K2 scans 128 segs,
// K3 parallel weighted lookback. K3 epilogue now stages Y in LDS and
// copies out coalesced (fixes 2.2x partial-line write amplification).

#define TT   262144
#define DIN  64
#define DS   128
#define DTC  0.01f
#define L    128
#define NG   (TT / L)        // 2048 chunks
#define SEGL 16
#define NSEG (NG / SEGL)     // 128 segments

typedef short  s8v  __attribute__((ext_vector_type(8)));
typedef short  s4v  __attribute__((ext_vector_type(4)));
typedef float  f4v  __attribute__((ext_vector_type(4)));

__device__ __forceinline__ unsigned short f2bf(float f) {
    unsigned u = __float_as_uint(f);
    u += 0x7fffu + ((u >> 16) & 1u);        // round-to-nearest-even
    return (unsigned short)(u >> 16);
}

__device__ __forceinline__ s8v pack8(float4 a, float4 b) {
    union { unsigned short u[8]; s8v v; } r;
    r.u[0] = f2bf(a.x); r.u[1] = f2bf(a.y); r.u[2] = f2bf(a.z); r.u[3] = f2bf(a.w);
    r.u[4] = f2bf(b.x); r.u[5] = f2bf(b.y); r.u[6] = f2bf(b.z); r.u[7] = f2bf(b.w);
    return r.v;
}

__device__ __forceinline__ s4v pack4(float x, float y, float z, float w) {
    union { unsigned short u[4]; s4v v; } r;
    r.u[0] = f2bf(x); r.u[1] = f2bf(y); r.u[2] = f2bf(z); r.u[3] = f2bf(w);
    return r.v;
}

// Fragment-granule LDS layout for bf16 matrix X[row][col], 8-col granules:
// ushort index = ((rtile*NCO + co)*16 + (mf ^ (co&15))) * 8.
__device__ __forceinline__ int gidx(int NCO, int rtile, int co, int mf) {
    return (((rtile * NCO + co) << 4) + (mf ^ (co & 15))) << 3;
}

__device__ __forceinline__ s8v ldfrag(const unsigned short* S, int NCO,
                                      int rtile, int kt, int q, int m) {
    return *(const s8v*)&S[gidx(NCO, rtile, kt * 4 + q, m)];
}

// Stage U chunk (128 x 64 fp32) -> bf16 A-frag granules.
__device__ __forceinline__ void stage_U(const float* __restrict__ Ug,
                                        unsigned short* __restrict__ sA,
                                        int tid) {
    #pragma unroll
    for (int p = 0; p < 2; ++p) {
        int u  = tid + p * 512;
        int co = u & 7, m = (u >> 3) & 15, mt = u >> 7;
        const float4* gp = (const float4*)(Ug + (mt * 16 + m) * DIN + co * 8);
        *(s8v*)&sA[gidx(8, mt, co, m)] = pack8(gp[0], gp[1]);
    }
}

__device__ __forceinline__ s8v load_bfrag(const float* __restrict__ M,
                                          int row, int k0, int ld) {
    const float4* p = (const float4*)(M + row * ld + k0);
    return pack8(p[0], p[1]);
}

// ---------------------------------------------------------------- K1
// agg[g][s] = sum_t a_s^(L-1-t) Bu[t,s]; weighted fold into segAgg (atomic).
__global__ __launch_bounds__(512, 8) void ssm_k1(
    const float* __restrict__ U, const float* __restrict__ Alog,
    const float* __restrict__ B, float* __restrict__ agg,
    float* __restrict__ segAgg)
{
    __shared__ __align__(16) unsigned short sA[8192];   // 16 KB
    const int g    = blockIdx.x;
    const int tid  = threadIdx.x;
    const int lane = tid & 63;
    const int w    = tid >> 6;
    const int q    = lane >> 4, m = lane & 15;
    const int s    = 16 * w + m;

    stage_U(U + (size_t)g * L * DIN, sA, tid);

    s8v Bf[2];
    #pragma unroll
    for (int ks = 0; ks < 2; ++ks)
        Bf[ks] = load_bfrag(B, s, ks * 32 + q * 8, DIN);

    const float cA = Alog[s] * DTC;
    __syncthreads();

    float ainv = __expf(-cA);
    float a16i = __expf(-16.f * cA);
    float wmt  = __expf(cA * (float)(127 - 4 * q));
    float wsum = 0.f;
    #pragma unroll
    for (int mt = 0; mt < 8; ++mt) {
        f4v acc = (f4v){0.f, 0.f, 0.f, 0.f};
        #pragma unroll
        for (int ks = 0; ks < 2; ++ks)
            acc = __builtin_amdgcn_mfma_f32_16x16x32_bf16(
                ldfrag(sA, 8, mt, ks, q, m), Bf[ks], acc, 0, 0, 0);
        float wr = wmt;
        #pragma unroll
        for (int r = 0; r < 4; ++r) {
            wsum = fmaf(wr, acc[r], wsum);
            wr *= ainv;
        }
        wmt *= a16i;
    }
    wsum += __shfl_xor(wsum, 16, 64);
    wsum += __shfl_xor(wsum, 32, 64);

    if (q == 0) {
        agg[(size_t)g * DS + s] = wsum;
        float wgt = __expf(cA * (float)(L * (SEGL - 1 - (g & (SEGL - 1)))));
        atomicAdd(&segAgg[(g >> 4) * DS + s], wsum * wgt);
    }
}

// ---------------------------------------------------------------- K2
// Serial scan over 128 segment aggregates -> segment carries + h_final.
__global__ void ssm_k2(const float* __restrict__ Alog, const float* __restrict__ h0,
                       const float* __restrict__ segAgg, float* __restrict__ segCarry,
                       float* __restrict__ hfin)
{
    const int s = threadIdx.x;                               // 128 threads
    const float aSeg = __expf(Alog[s] * (DTC * L * SEGL));
    float c = h0[s];
    #pragma unroll 8
    for (int sg = 0; sg < NSEG; ++sg) {
        segCarry[sg * DS + s] = c;
        c = fmaf(aSeg, c, segAgg[sg * DS + s]);
    }
    hfin[s] = c;
}

// ---------------------------------------------------------------- K3
__global__ __launch_bounds__(512, 6) void ssm_k3(
    const float* __restrict__ U, const float* __restrict__ Alog,
    const float* __restrict__ B, const float* __restrict__ C,
    const float* __restrict__ Dm, const float* __restrict__ agg,
    const float* __restrict__ segCarry, float* __restrict__ Y)
{
    __shared__ __align__(16) unsigned char smem[49152];      // 48 KB
    unsigned short* sA = (unsigned short*)smem;              // 16 KB U frags
    unsigned short* sT = (unsigned short*)(smem + 16384);    // 32 KB Bu'^T / H^T
    float*          sY = (float*)smem;                       // overlay, 128x68 f32
    __shared__ float sCA[DS];
    __shared__ float sDc[DS];

    const int g    = blockIdx.x;
    const int tid  = threadIdx.x;
    const int lane = tid & 63;
    const int w    = tid >> 6;
    const int q    = lane >> 4, m = lane & 15;

    s8v Bf[2];
    #pragma unroll
    for (int ks = 0; ks < 2; ++ks)
        Bf[ks] = load_bfrag(B, 16 * w + m, ks * 32 + q * 8, DIN);
    const float cA = Alog[16 * w + m] * DTC;

    stage_U(U + (size_t)g * L * DIN, sA, tid);

    // carry via parallel weighted lookback over <=15 L2-hot agg rows
    if (tid < DS) {
        const float ca  = Alog[tid] * DTC;
        sCA[tid] = ca;
        const float caL = ca * (float)L;
        const float aL  = __expf(caL);
        const int   j   = g & (SEGL - 1);
        const int   gb  = g & ~(SEGL - 1);
        float c0 = segCarry[(g >> 4) * DS + tid] * __expf(caL * (float)j);
        float wt = 1.f;
        for (int c = j - 1; c >= 0; --c) {
            c0 = fmaf(wt, agg[(size_t)(gb + c) * DS + tid], c0);
            wt *= aL;
        }
        sDc[tid] = __expf(ca) * c0;             // a_s * carry_s
    }
    __syncthreads();                                     // B1

    // ---- GEMM1 + scale by a_s^-t, transpose-store Bu'^T[s][t]
    {
        float ainv = __expf(-cA);
        float a16i = __expf(-16.f * cA);
        float fmt  = __expf(-cA * (float)(4 * q));
        #pragma unroll
        for (int mt = 0; mt < 8; ++mt) {
            f4v acc = (f4v){0.f, 0.f, 0.f, 0.f};
            #pragma unroll
            for (int ks = 0; ks < 2; ++ks)
                acc = __builtin_amdgcn_mfma_f32_16x16x32_bf16(
                    ldfrag(sA, 8, mt, ks, q, m), Bf[ks], acc, 0, 0, 0);
            float f0 = fmt, f1 = f0 * ainv, f2 = f1 * ainv, f3 = f2 * ainv;
            s4v pk = pack4(acc[0] * f0, acc[1] * f1, acc[2] * f2, acc[3] * f3);
            *(s4v*)&sT[gidx(16, w, mt * 2 + (q >> 1), m) + (q & 1) * 4] = pk;
            fmt *= a16i;
        }
    }
    __syncthreads();                                     // B2

    // ---- Tri-GEMM: H'^T[s,t] = sum_{tau<=t} Bu'^T[s,tau]
    const int KBmax = w >> 1;
    const int thr   = m + 16 * (w & 1);
    s8v ones, part;
    {
        union { unsigned short u[8]; s8v v; } o, p;
        #pragma unroll
        for (int j = 0; j < 8; ++j) {
            o.u[j] = 0x3F80;
            p.u[j] = (q * 8 + j <= thr) ? 0x3F80 : 0;
        }
        ones = o.v; part = p.v;
    }
    const float tf = (float)(16 * w + m);
    s4v pk[8];
    #pragma unroll
    for (int grp = 0; grp < 2; ++grp) {
        f4v acc[4];
        #pragma unroll
        for (int i = 0; i < 4; ++i) acc[i] = (f4v){0.f, 0.f, 0.f, 0.f};
        for (int kb = 0; kb <= KBmax; ++kb) {
            s8v bfr = (kb < KBmax) ? ones : part;
            #pragma unroll
            for (int msl = 0; msl < 4; ++msl)
                acc[msl] = __builtin_amdgcn_mfma_f32_16x16x32_bf16(
                    ldfrag(sT, 16, grp * 4 + msl, kb, q, m), bfr, acc[msl], 0, 0, 0);
        }
        #pragma unroll
        for (int msl = 0; msl < 4; ++msl) {
            const int ms = grp * 4 + msl;
            const float4 cav = *(const float4*)&sCA[16 * ms + 4 * q];
            const float4 dcv = *(const float4*)&sDc[16 * ms + 4 * q];
            pk[grp * 4 + msl] = pack4(
                __expf(cav.x * tf) * (acc[msl][0] + dcv.x),
                __expf(cav.y * tf) * (acc[msl][1] + dcv.y),
                __expf(cav.z * tf) * (acc[msl][2] + dcv.z),
                __expf(cav.w * tf) * (acc[msl][3] + dcv.w));
        }
    }

    // C/D raw loads (latency overlapped with barriers + sT writes)
    const int mi = w & 3, th = w >> 2;
    float4 craw[4][2], draw[2][2];
    #pragma unroll
    for (int ks = 0; ks < 4; ++ks) {
        const float4* p = (const float4*)(C + (16 * mi + m) * DS + ks * 32 + q * 8);
        craw[ks][0] = p[0]; craw[ks][1] = p[1];
    }
    #pragma unroll
    for (int ks = 0; ks < 2; ++ks) {
        const float4* p = (const float4*)(Dm + (16 * mi + m) * DIN + ks * 32 + q * 8);
        draw[ks][0] = p[0]; draw[ks][1] = p[1];
    }

    __syncthreads();                                     // B3
    #pragma unroll
    for (int ms = 0; ms < 8; ++ms)
        *(s4v*)&sT[gidx(16, w, ms * 2 + (q >> 1), m) + (q & 1) * 4] = pk[ms];
    __syncthreads();                                     // B4

    // ---- GEMM2: (M=i, N=t) tiles; accs held in regs until B5
    s8v Cf[4], Df[2];
    #pragma unroll
    for (int ks = 0; ks < 4; ++ks) Cf[ks] = pack8(craw[ks][0], craw[ks][1]);
    #pragma unroll
    for (int ks = 0; ks < 2; ++ks) Df[ks] = pack8(draw[ks][0], draw[ks][1]);

    f4v acc2[4];
    #pragma unroll
    for (int nn = 0; nn < 4; ++nn) {
        const int nt2 = th * 4 + nn;
        f4v a2 = (f4v){0.f, 0.f, 0.f, 0.f};
        #pragma unroll
        for (int ks = 0; ks < 4; ++ks)
            a2 = __builtin_amdgcn_mfma_f32_16x16x32_bf16(
                Cf[ks], ldfrag(sT, 16, nt2, ks, q, m), a2, 0, 0, 0);
        #pragma unroll
        for (int ks = 0; ks < 2; ++ks)
            a2 = __builtin_amdgcn_mfma_f32_16x16x32_bf16(
                Df[ks], ldfrag(sA, 8, nt2, ks, q, m), a2, 0, 0, 0);
        acc2[nn] = a2;
    }
    __syncthreads();                                     // B5: all LDS reads done

    // stage Y in LDS (stride 68: <=2-way banks), then coalesced copy-out
    #pragma unroll
    for (int nn = 0; nn < 4; ++nn) {
        const int t = 16 * (th * 4 + nn) + m;
        *(f4v*)&sY[t * 68 + 16 * mi + 4 * q] = acc2[nn];
    }
    __syncthreads();                                     // B6

    float* Yb = Y + (size_t)g * L * DIN;
    {
        const int t0 = tid >> 2, iseg = (tid & 3) * 16;
        #pragma unroll
        for (int rr = 0; rr < 1; ++rr) { }               // (single round: 512 thr x 4 f4 = 8KB? no:)
        // 128 rows x 64 cols: thread (t0, iseg) handles 16 floats of row t0
        const float4* sp = (const float4*)&sY[t0 * 68 + iseg];
        float4* gp = (float4*)(Yb + t0 * 64 + iseg);
        float4 v0 = sp[0], v1 = sp[1], v2 = sp[2], v3 = sp[3];
        gp[0] = v0; gp[1] = v1; gp[2] = v2; gp[3] = v3;
    }
}

// ---------------------------------------------------------------- launch
extern "C" void kernel_launch(void* const* d_in, const int* in_sizes, int n_in,
                              void* d_out, int out_size, void* d_ws, size_t ws_size,
                              hipStream_t stream)
{
    const float* U    = (const float*)d_in[0];
    const float* Alog = (const float*)d_in[1];
    const float* B    = (const float*)d_in[2];
    const float* C    = (const float*)d_in[3];
    const float* Dm   = (const float*)d_in[4];
    const float* h0   = (const float*)d_in[5];

    float* out  = (float*)d_out;
    float* Yp   = out;                        // T*DIN
    float* hfin = out + (size_t)TT * DIN;     // 128

    float* agg      = (float*)d_ws;                 // NG*DS    (1 MB)
    float* segAgg   = agg + (size_t)NG * DS;        // NSEG*DS  (64 KB)
    float* segCarry = segAgg + (size_t)NSEG * DS;   // NSEG*DS  (64 KB)

    hipMemsetAsync(segAgg, 0, (size_t)NSEG * DS * sizeof(float), stream);
    ssm_k1<<<NG, 512, 0, stream>>>(U, Alog, B, agg, segAgg);
    ssm_k2<<<1, DS, 0, stream>>>(Alog, h0, segAgg, segCarry, hfin);
    ssm_k3<<<NG, 512, 0, stream>>>(U, Alog, B, C, Dm, agg, segCarry, Yp);
}